// Round 9
// baseline (878.074 us; speedup 1.0000x reference)
//
#include <hip/hip_runtime.h>
#include <hip/hip_bf16.h>
#include <math.h>

#define B 32
#define S 1024
#define IN_DIM 16
#define E 128
#define NH 4
#define DH 32
#define HDIM 256
#define ROWS (B*S)   /* 32768 */
#define EPS 1e-5f

#define N_IPW (3*384*128)
#define N_SQ  (3*128*128)
#define NCVT ((N_IPW + 3*N_SQ) / 256)   /* 1152 cvt blocks */

typedef __bf16 bf16x8 __attribute__((ext_vector_type(8)));
typedef __bf16 bf16x4 __attribute__((ext_vector_type(4)));
typedef __bf16 bf16x2 __attribute__((ext_vector_type(2)));
typedef float f32x4 __attribute__((ext_vector_type(4)));
typedef float f32x16 __attribute__((ext_vector_type(16)));

#define MFMA16 __builtin_amdgcn_mfma_f32_16x16x32_bf16
#define MFMA32 __builtin_amdgcn_mfma_f32_32x32x16_bf16

union BF2U { bf16x2 b; unsigned int u; };
__device__ inline unsigned int pk2(float a, float b) {
    BF2U x; x.b[0] = (__bf16)a; x.b[1] = (__bf16)b; return x.u;
}

// 16B logical access as two 8B LDS ops.
union U8 { bf16x8 v8; bf16x4 v4[2]; unsigned u4[4]; };
__device__ inline void st8(__bf16* p, bf16x8 v) {
    U8 u; u.v8 = v;
    *(bf16x4*)p = u.v4[0];
    *(bf16x4*)(p + 4) = u.v4[1];
}
__device__ inline bf16x8 ld8(const __bf16* p) {
    U8 u;
    u.v4[0] = *(const bf16x4*)p;
    u.v4[1] = *(const bf16x4*)(p + 4);
    return u.v8;
}

// ---------------- fused weight-cvt + embed ----------------
__global__ __launch_bounds__(256) void k_embedcvt(
        const float* __restrict__ ipw, const float* __restrict__ ow,
        const float* __restrict__ w1, const float* __restrict__ w2,
        __bf16* __restrict__ wbo,
        const float* __restrict__ x, const float* __restrict__ W,
        const float* __restrict__ bias, __bf16* __restrict__ hb)
{
    int t = threadIdx.x;
    if (blockIdx.x < NCVT) {
        int i = blockIdx.x * 256 + t;
        float v;
        if (i < N_IPW) v = ipw[i];
        else if (i < N_IPW + N_SQ) v = ow[i - N_IPW];
        else if (i < N_IPW + 2 * N_SQ) v = w1[i - N_IPW - N_SQ];
        else v = w2[i - N_IPW - 2 * N_SQ];
        wbo[i] = (__bf16)v;
        return;
    }
    int row0 = (blockIdx.x - NCVT) * 16;
    __shared__ float xs[16][16];
    xs[t >> 4][t & 15] = x[(row0 + (t >> 4)) * IN_DIM + (t & 15)];
    __syncthreads();
    int sub = t >> 7, tc = t & 127;
    float w[16];
#pragma unroll
    for (int i = 0; i < 16; ++i) w[i] = W[tc * 16 + i];
    float bb = bias[tc];
#pragma unroll
    for (int rr = 0; rr < 8; ++rr) {
        int lr = sub * 8 + rr;
        float acc = bb;
#pragma unroll
        for (int i = 0; i < 16; ++i) acc += xs[lr][i] * w[i];
        hb[(size_t)(row0 + lr) * E + tc] = (__bf16)fmaxf(acc, 0.f);
    }
}

// ---------------- fused QKV-projection + flash attention (R9) ----------------
// R8 + the remaining-spill fix: peak live >128 came from `#pragma unroll` on
// the phase-2 c2 loops — full unroll let the scheduler hoist 4x af[4] load
// groups (64 VGPRs in flight) on top of bWk(32)+o(16)+bQ(8) -> >128 -> f32x16
// spill (293 MB WRITE_SIZE). `#pragma unroll 1` caps af at 16 live; peak ~95.
// 4 waves/SIMD (2 independent blocks/CU) covers the un-hoisted load latency.
__global__ __launch_bounds__(512, 2) void k_qkvattn(
        const __bf16* __restrict__ hb, const __bf16* __restrict__ Wip,
        const float* __restrict__ bip, __bf16* __restrict__ O)
{
    __shared__ __attribute__((aligned(16))) __bf16 Kst[512][36];
    __shared__ __attribute__((aligned(16))) __bf16 Vst[32][524];  // 262dw%32=6 -> ~2-way max
    __shared__ float lscr[8][32];

    int t = threadIdx.x, lane = t & 63, wv = t >> 6;   // wv 0..7
    int l15 = lane & 15, quad = lane >> 4;
    int l31 = lane & 31, hi = lane >> 5;
    // XCD grouping: 64 consecutive logical blocks (= 4 full b-panels) per XCD.
    int lb = (blockIdx.x & 7) * 64 + (blockIdx.x >> 3);
    int qd = lb & 3;            // q-quarter: rows qd*256 .. +255
    int bh = lb >> 2;
    int hh = bh & 3, b = bh >> 2;

    const __bf16* hpanel = hb + (size_t)b * S * E;

    // scale * log2(e) * 2^23 (Schraudolph pre-scale)
    const float qscale = 0.1767766952966369f * 1.4426950408889634f * 8388608.0f;
    const float C2 = 1065101558.0f;   // (127<<23) - 0.03*2^23
    f32x16 cinit16, z16;
#pragma unroll
    for (int i = 0; i < 16; ++i) { cinit16[i] = C2; z16[i] = 0.f; }

    // ---------- phase 1: Q for this wave's 32 rows, 32x32 path ----------
    // D[q][d]: lane=d. One-time transpose to B-frag (lane=q, regs=d) via a
    // per-wave [32][36] scratch slice aliased into Kst rows wv*32..+31.
    bf16x8 bQ[2];
    {
        bf16x8 bWq[8];
#pragma unroll
        for (int ch = 0; ch < 8; ++ch)
            bWq[ch] = *(const bf16x8*)&Wip[(size_t)(hh*32 + l31)*128 + ch*16 + hi*8];
        float bq = bip[hh*32 + l31];
        int qrow0 = qd*256 + wv*32;
        f32x16 aq = z16;
#pragma unroll
        for (int ch = 0; ch < 8; ++ch) {
            bf16x8 ah = *(const bf16x8*)&hpanel[(size_t)(qrow0 + l31)*128 + ch*16 + hi*8];
            aq = MFMA32(ah, bWq[ch], aq, 0, 0, 0);
        }
        __bf16* PmS = &Kst[wv*32][0];
#pragma unroll
        for (int r = 0; r < 16; ++r) {
            int q = (r & 3) + 8*(r >> 2) + 4*hi;
            PmS[q*36 + l31] = (__bf16)((aq[r] + bq) * qscale);
        }
        __asm__ __volatile__("" ::: "memory");
        bQ[0] = ld8(&PmS[l31*36 + hi*8]);
        bQ[1] = ld8(&PmS[l31*36 + 16 + hi*8]);
        __asm__ __volatile__("" ::: "memory");
    }
    __syncthreads();   // scratch rows are about to be overwritten by K fill

    f32x16 o = z16;
    float lsum = 0.f;
    const f32x4 z4 = {0.f, 0.f, 0.f, 0.f};

    for (int half = 0; half < 2; ++half) {
        int srow = wv*16 + l15;   // 8 waves x 16 rows = 128 s-rows per iter
        // ---------- phase 2a: K projection (only K weights live) ----------
        {
            bf16x8 bWk[2][4];
#pragma unroll
            for (int df = 0; df < 2; ++df)
#pragma unroll
                for (int kc = 0; kc < 4; ++kc)
                    bWk[df][kc] = *(const bf16x8*)&Wip[(size_t)(128 + hh*32 + df*16 + l15)*128 + kc*32 + quad*8];
            float bk0 = bip[128 + hh*32 + l15], bk1 = bip[128 + hh*32 + 16 + l15];
#pragma unroll 1
            for (int c2 = 0; c2 < 4; ++c2) {
                bf16x8 af[4];
#pragma unroll
                for (int kc = 0; kc < 4; ++kc)
                    af[kc] = *(const bf16x8*)&hpanel[(size_t)(half*512 + c2*128 + srow)*128 + kc*32 + quad*8];
                f32x4 k0 = z4, k1 = z4;
#pragma unroll
                for (int kc = 0; kc < 4; ++kc) {
                    k0 = MFMA16(af[kc], bWk[0][kc], k0, 0, 0, 0);
                    k1 = MFMA16(af[kc], bWk[1][kc], k1, 0, 0, 0);
                }
                int s0 = c2*128 + wv*16 + quad*4;
#pragma unroll
                for (int r = 0; r < 4; ++r) {
                    Kst[s0 + r][l15]      = (__bf16)(k0[r] + bk0);
                    Kst[s0 + r][16 + l15] = (__bf16)(k1[r] + bk1);
                }
            }
        }
        __asm__ __volatile__("" ::: "memory");
        // ---------- phase 2b: V projection (only V weights live) ----------
        {
            bf16x8 bWv[2][4];
#pragma unroll
            for (int df = 0; df < 2; ++df)
#pragma unroll
                for (int kc = 0; kc < 4; ++kc)
                    bWv[df][kc] = *(const bf16x8*)&Wip[(size_t)(256 + hh*32 + df*16 + l15)*128 + kc*32 + quad*8];
            float bvb0 = bip[256 + hh*32 + l15], bvb1 = bip[256 + hh*32 + 16 + l15];
#pragma unroll 1
            for (int c2 = 0; c2 < 4; ++c2) {
                bf16x8 af[4];
#pragma unroll
                for (int kc = 0; kc < 4; ++kc)
                    af[kc] = *(const bf16x8*)&hpanel[(size_t)(half*512 + c2*128 + srow)*128 + kc*32 + quad*8];
                f32x4 v0 = z4, v1 = z4;
#pragma unroll
                for (int kc = 0; kc < 4; ++kc) {
                    v0 = MFMA16(af[kc], bWv[0][kc], v0, 0, 0, 0);
                    v1 = MFMA16(af[kc], bWv[1][kc], v1, 0, 0, 0);
                }
                int s0 = c2*128 + wv*16 + quad*4;
                uint2 u0, u1;
                u0.x = pk2(v0[0] + bvb0, v0[1] + bvb0);
                u0.y = pk2(v0[2] + bvb0, v0[3] + bvb0);
                u1.x = pk2(v1[0] + bvb1, v1[1] + bvb1);
                u1.y = pk2(v1[2] + bvb1, v1[3] + bvb1);
                *(uint2*)&Vst[l15][s0] = u0;
                *(uint2*)&Vst[16 + l15][s0] = u1;
            }
        }
        __syncthreads();

        // ---------- phase 3: attention over this 512-row KV chunk ----------
        for (int c = 0; c < 8; ++c) {
            bf16x8 aK[2][2];
#pragma unroll
            for (int sub = 0; sub < 2; ++sub)
#pragma unroll
                for (int dh = 0; dh < 2; ++dh)
                    aK[sub][dh] = ld8(&Kst[c*64 + sub*32 + l31][dh*16 + hi*8]);
            bf16x8 bVf[4];
#pragma unroll
            for (int ch = 0; ch < 4; ++ch) {
                U8 u;
                const __bf16* vp = &Vst[l31][c*64 + ch*16 + hi*4];
                u.v4[0] = *(const bf16x4*)vp;        // k = ch*16 + 4hi + 0..3
                u.v4[1] = *(const bf16x4*)(vp + 8);  // k = ch*16 + 8 + 4hi + 0..3
                bVf[ch] = u.v8;
            }
#pragma unroll
            for (int sub = 0; sub < 2; ++sub) {
                f32x16 acc = cinit16;
                acc = MFMA32(aK[sub][0], bQ[0], acc, 0, 0, 0);
                acc = MFMA32(aK[sub][1], bQ[1], acc, 0, 0, 0);
                // S[k][q] at lane(hi,q): k = 4hi + {0-3,8-11} (+16 for g=1).
                // Packed dwords are directly the PV A-frag; ints reinterpret
                // as f32 exp for the VALU row-sum.
#pragma unroll
                for (int g = 0; g < 2; ++g) {
                    U8 u;
                    float ls = 0.f;
#pragma unroll
                    for (int r = 0; r < 4; ++r) {
                        int ia = (int)acc[g*8 + 2*r];
                        int ib = (int)acc[g*8 + 2*r + 1];
                        u.u4[r] = __builtin_amdgcn_perm((unsigned)ib, (unsigned)ia, 0x07060302u);
                        ls += __int_as_float(ia) + __int_as_float(ib);
                    }
                    lsum += ls;
                    o = MFMA32(u.v8, bVf[sub*2 + g], o, 0, 0, 0);
                }
            }
        }
        if (half == 0) __syncthreads();   // before next fill overwrites LDS
    }

    // ---------- epilogue: combine l halves, transpose 1/l via lscr ----------
    lsum += __shfl_xor(lsum, 32);
    if (hi == 0) lscr[wv][l31] = 1.f / lsum;
    __asm__ __volatile__("" ::: "memory");
#pragma unroll
    for (int r = 0; r < 16; ++r) {
        int q = (r & 3) + 8*(r >> 2) + 4*hi;
        float li = lscr[wv][q];
        int row = qd*256 + wv*32 + q;
        O[((size_t)(b * S) + row) * E + hh*32 + l31] = (__bf16)(o[r] * li);
    }
}

// ---------------- mega-fused: out-proj + res + LN1 + FFN1 + FFN2 + res + LN2 ----------------
// (512,2): grid is exactly 2 blocks/CU; cap 128, no spill.
__global__ __launch_bounds__(512, 2) void k_layer2(const __bf16* __restrict__ t0b,
        const __bf16* __restrict__ Wo, const float* __restrict__ ob,
        const float* __restrict__ g1, const float* __restrict__ bt1,
        const __bf16* __restrict__ W1, const float* __restrict__ b1v,
        const __bf16* __restrict__ W2, const float* __restrict__ b2v,
        const float* __restrict__ g2, const float* __restrict__ bt2,
        __bf16* __restrict__ hb)
{
    __shared__ __attribute__((aligned(16))) __bf16 As[64][132];
    __shared__ __attribute__((aligned(16))) __bf16 Ws[128][132];
    __shared__ float red[2][64][2];
    int t = threadIdx.x;
    int m0 = blockIdx.x * 64;
    int arow = t >> 3, acol = (t & 7) * 16;
    int wrow = t >> 2, wcol = (t & 3) * 32;
    {
        const __bf16* Ap = t0b + (size_t)(m0 + arow) * 128 + acol;
#pragma unroll
        for (int j = 0; j < 2; ++j)
            st8(&As[arow][acol + j * 8], *(const bf16x8*)&Ap[j * 8]);
        const __bf16* Wp = Wo + (size_t)wrow * 128 + wcol;
#pragma unroll
        for (int j = 0; j < 4; ++j)
            st8(&Ws[wrow][wcol + j * 8], *(const bf16x8*)&Wp[j * 8]);
    }
    __syncthreads();
    int lane = t & 63, wv = t >> 6;
    int l15 = lane & 15, quad = lane >> 4;
    int nh = wv & 1, mh = wv >> 1;   // mh 0..3: rows mh*16..+15
    f32x4 acc[4];

    // ---------- phase A: out-proj ----------
#pragma unroll
    for (int i = 0; i < 4; ++i) acc[i] = (f32x4){0.f, 0.f, 0.f, 0.f};
#pragma unroll
    for (int kc = 0; kc < 4; ++kc) {
        bf16x8 aw[4], ba;
#pragma unroll
        for (int nc = 0; nc < 4; ++nc)
            aw[nc] = ld8(&Ws[nh * 64 + nc * 16 + l15][kc * 32 + quad * 8]);
        ba = ld8(&As[mh * 16 + l15][kc * 32 + quad * 8]);
#pragma unroll
        for (int nc = 0; nc < 4; ++nc)
            acc[nc] = MFMA16(aw[nc], ba, acc[nc], 0, 0, 0);
    }
    float s1 = 0.f, s2 = 0.f;
    int m = m0 + mh * 16 + l15;
#pragma unroll
    for (int nc = 0; nc < 4; ++nc) {
        float4 bv = *(const float4*)&ob[nh * 64 + nc * 16 + quad * 4];
        bf16x4 rv = *(const bf16x4*)&hb[(size_t)m * 128 + nh * 64 + nc * 16 + quad * 4];
        acc[nc][0] += bv.x + (float)rv[0];
        acc[nc][1] += bv.y + (float)rv[1];
        acc[nc][2] += bv.z + (float)rv[2];
        acc[nc][3] += bv.w + (float)rv[3];
#pragma unroll
        for (int i = 0; i < 4; ++i) {
            s1 += acc[nc][i];
            s2 += acc[nc][i] * acc[nc][i];
        }
    }
    s1 += __shfl_xor(s1, 16); s1 += __shfl_xor(s1, 32);
    s2 += __shfl_xor(s2, 16); s2 += __shfl_xor(s2, 32);
    if (quad == 0) {
        red[nh][mh * 16 + l15][0] = s1;
        red[nh][mh * 16 + l15][1] = s2;
    }
    __syncthreads();
    float mu, rs;
    {
        int r = mh * 16 + l15;
        float S1 = red[0][r][0] + red[1][r][0];
        float S2 = red[0][r][1] + red[1][r][1];
        mu = S1 * (1.f / 128.f);
        float var = S2 * (1.f / 128.f) - mu * mu;
        rs = rsqrtf(var + EPS);
    }
    bf16x4 res2[4];
#pragma unroll
    for (int nc = 0; nc < 4; ++nc) {
        float4 gv = *(const float4*)&g1[nh * 64 + nc * 16 + quad * 4];
        float4 bb = *(const float4*)&bt1[nh * 64 + nc * 16 + quad * 4];
        float o0 = (acc[nc][0] - mu) * rs * gv.x + bb.x;
        float o1 = (acc[nc][1] - mu) * rs * gv.y + bb.y;
        float o2 = (acc[nc][2] - mu) * rs * gv.z + bb.z;
        float o3 = (acc[nc][3] - mu) * rs * gv.w + bb.w;
        bf16x4 xb;
        xb[0] = (__bf16)o0; xb[1] = (__bf16)o1;
        xb[2] = (__bf16)o2; xb[3] = (__bf16)o3;
        res2[nc] = xb;
        *(bf16x4*)&As[mh * 16 + l15][nh * 64 + nc * 16 + quad * 4] = xb;
    }
    {
        const __bf16* Wp = W1 + (size_t)wrow * 128 + wcol;
#pragma unroll
        for (int j = 0; j < 4; ++j)
            st8(&Ws[wrow][wcol + j * 8], *(const bf16x8*)&Wp[j * 8]);
    }
    __syncthreads();

    // ---------- phase B: FFN1 ----------
#pragma unroll
    for (int i = 0; i < 4; ++i) acc[i] = (f32x4){0.f, 0.f, 0.f, 0.f};
#pragma unroll
    for (int kc = 0; kc < 4; ++kc) {
        bf16x8 aw[4], ba;
#pragma unroll
        for (int nc = 0; nc < 4; ++nc)
            aw[nc] = ld8(&Ws[nh * 64 + nc * 16 + l15][kc * 32 + quad * 8]);
        ba = ld8(&As[mh * 16 + l15][kc * 32 + quad * 8]);
#pragma unroll
        for (int nc = 0; nc < 4; ++nc)
            acc[nc] = MFMA16(aw[nc], ba, acc[nc], 0, 0, 0);
    }
    __syncthreads();
#pragma unroll
    for (int nc = 0; nc < 4; ++nc) {
        float4 bv = *(const float4*)&b1v[nh * 64 + nc * 16 + quad * 4];
        float v0 = fmaxf(acc[nc][0] + bv.x, 0.f);
        float v1 = fmaxf(acc[nc][1] + bv.y, 0.f);
        float v2 = fmaxf(acc[nc][2] + bv.z, 0.f);
        float v3 = fmaxf(acc[nc][3] + bv.w, 0.f);
        uint2 u; u.x = pk2(v0, v1); u.y = pk2(v2, v3);
        *(uint2*)&As[mh * 16 + l15][nh * 64 + nc * 16 + quad * 4] = u;
    }
    {
        const __bf16* Wp = W2 + (size_t)wrow * 128 + wcol;
#pragma unroll
        for (int j = 0; j < 4; ++j)
            st8(&Ws[wrow][wcol + j * 8], *(const bf16x8*)&Wp[j * 8]);
    }
    __syncthreads();

    // ---------- phase C: FFN2 + res2 + LN2 ----------
#pragma unroll
    for (int i = 0; i < 4; ++i) acc[i] = (f32x4){0.f, 0.f, 0.f, 0.f};
#pragma unroll
    for (int kc = 0; kc < 4; ++kc) {
        bf16x8 aw[4], ba;
#pragma unroll
        for (int nc = 0; nc < 4; ++nc)
            aw[nc] = ld8(&Ws[nh * 64 + nc * 16 + l15][kc * 32 + quad * 8]);
        ba = ld8(&As[mh * 16 + l15][kc * 32 + quad * 8]);
#pragma unroll
        for (int nc = 0; nc < 4; ++nc)
            acc[nc] = MFMA16(aw[nc], ba, acc[nc], 0, 0, 0);
    }
    s1 = 0.f; s2 = 0.f;
#pragma unroll
    for (int nc = 0; nc < 4; ++nc) {
        float4 bv = *(const float4*)&b2v[nh * 64 + nc * 16 + quad * 4];
        acc[nc][0] += bv.x + (float)res2[nc][0];
        acc[nc][1] += bv.y + (float)res2[nc][1];
        acc[nc][2] += bv.z + (float)res2[nc][2];
        acc[nc][3] += bv.w + (float)res2[nc][3];
#pragma unroll
        for (int i = 0; i < 4; ++i) {
            s1 += acc[nc][i];
            s2 += acc[nc][i] * acc[nc][i];
        }
    }
    s1 += __shfl_xor(s1, 16); s1 += __shfl_xor(s1, 32);
    s2 += __shfl_xor(s2, 16); s2 += __shfl_xor(s2, 32);
    if (quad == 0) {
        red[nh][mh * 16 + l15][0] = s1;
        red[nh][mh * 16 + l15][1] = s2;
    }
    __syncthreads();
    {
        int r = mh * 16 + l15;
        float S1 = red[0][r][0] + red[1][r][0];
        float S2 = red[0][r][1] + red[1][r][1];
        mu = S1 * (1.f / 128.f);
        float var = S2 * (1.f / 128.f) - mu * mu;
        rs = rsqrtf(var + EPS);
    }
#pragma unroll
    for (int nc = 0; nc < 4; ++nc) {
        float4 gv = *(const float4*)&g2[nh * 64 + nc * 16 + quad * 4];
        float4 bb = *(const float4*)&bt2[nh * 64 + nc * 16 + quad * 4];
        float o0 = (acc[nc][0] - mu) * rs * gv.x + bb.x;
        float o1 = (acc[nc][1] - mu) * rs * gv.y + bb.y;
        float o2 = (acc[nc][2] - mu) * rs * gv.z + bb.z;
        float o3 = (acc[nc][3] - mu) * rs * gv.w + bb.w;
        uint2 u; u.x = pk2(o0, o1); u.y = pk2(o2, o3);
        *(uint2*)&hb[(size_t)m * 128 + nh * 64 + nc * 16 + quad * 4] = u;
    }
}

// ---------------- masked sum pool stage 1 (bf16 h, vectorized) ----------------
__global__ __launch_bounds__(256) void k_pool1(const __bf16* __restrict__ h,
        const float* __restrict__ mask, float* __restrict__ part)
{
    int bx = blockIdx.x;
    int b = bx >> 3, ch = bx & 7, t = threadIdx.x;
    int sg = t >> 4, cg = t & 15;
    __shared__ float red[16][128];
    float acc[8];
#pragma unroll
    for (int j = 0; j < 8; ++j) acc[j] = 0.f;
    const __bf16* hp = h + ((size_t)(b * S + ch * 128 + sg)) * E + cg * 8;
    const float* mp = mask + b * S + ch * 128 + sg;
#pragma unroll
    for (int k = 0; k < 8; ++k) {
        float m = mp[k * 16];
        bf16x8 hv = *(const bf16x8*)&hp[(size_t)(k * 16) * E];
#pragma unroll
        for (int j = 0; j < 8; ++j) acc[j] += (float)hv[j] * m;
    }
#pragma unroll
    for (int j = 0; j < 8; ++j) red[sg][cg * 8 + j] = acc[j];
    __syncthreads();
    if (t < 128) {
        float a = 0.f;
#pragma unroll
        for (int sgi = 0; sgi < 16; ++sgi) a += red[sgi][t];
        part[(size_t)bx * E + t] = a;
    }
}

// ---------------- fused head: pool2 + cls1..3 + final sigmoid ----------------
__global__ __launch_bounds__(256) void k_head(const float* __restrict__ part,
        const float* __restrict__ cw1, const float* __restrict__ cb1,
        const float* __restrict__ cw2, const float* __restrict__ cb2,
        const float* __restrict__ cw3, const float* __restrict__ cb3,
        const float* __restrict__ cw4, const float* __restrict__ cb4,
        float* __restrict__ out)
{
    int b = blockIdx.x, t = threadIdx.x;
    __shared__ float p[128], za[256], zb[256];
    __shared__ float red4[4];
    if (t < 128) {
        float a = 0.f;
#pragma unroll
        for (int c = 0; c < 8; ++c) a += part[(size_t)(b * 8 + c) * 128 + t];
        p[t] = a;
    }
    __syncthreads();
    float a1 = cb1[t];
    for (int k = 0; k < 128; ++k) a1 += p[k] * cw1[t * 128 + k];
    za[t] = fmaxf(a1, 0.f);
    __syncthreads();
    float a2 = cb2[t];
    for (int k = 0; k < 256; ++k) a2 += za[k] * cw2[t * 256 + k];
    zb[t] = fmaxf(a2, 0.f);
    __syncthreads();
    float a3 = cb3[t];
    for (int k = 0; k < 256; ++k) a3 += zb[k] * cw3[t * 256 + k];
    float z3 = fmaxf(a3, 0.f);
    float prt = z3 * cw4[t];
#pragma unroll
    for (int o2 = 32; o2; o2 >>= 1) prt += __shfl_xor(prt, o2);
    if ((t & 63) == 0) red4[t >> 6] = prt;
    __syncthreads();
    if (t == 0) {
        float sum = red4[0] + red4[1] + red4[2] + red4[3] + cb4[0];
        out[b] = 1.f / (1.f + __expf(-sum));
    }
}

extern "C" void kernel_launch(void* const* d_in, const int* in_sizes, int n_in,
                              void* d_out, int out_size, void* d_ws, size_t ws_size,
                              hipStream_t stream)
{
    const float* x     = (const float*)d_in[0];
    const float* mask  = (const float*)d_in[1];
    const float* emb_w = (const float*)d_in[2];
    const float* emb_b = (const float*)d_in[3];
    const float* ipw   = (const float*)d_in[4];
    const float* ipb   = (const float*)d_in[5];
    const float* ow    = (const float*)d_in[6];
    const float* ob    = (const float*)d_in[7];
    const float* ln1g  = (const float*)d_in[8];
    const float* ln1b  = (const float*)d_in[9];
    const float* ln2g  = (const float*)d_in[10];
    const float* ln2b  = (const float*)d_in[11];
    const float* w1    = (const float*)d_in[12];
    const float* fb1   = (const float*)d_in[13];
    const float* w2    = (const float*)d_in[14];
    const float* fb2   = (const float*)d_in[15];
    const float* cw1   = (const float*)d_in[16];
    const float* cb1   = (const float*)d_in[17];
    const float* cw2   = (const float*)d_in[18];
    const float* cb2   = (const float*)d_in[19];
    const float* cw3   = (const float*)d_in[20];
    const float* cb3   = (const float*)d_in[21];
    const float* cw4   = (const float*)d_in[22];
    const float* cb4   = (const float*)d_in[23];

    char* p = (char*)d_ws;
    __bf16* hb   = (__bf16*)p;   p += (size_t)ROWS * E * 2;        // 8 MB bf16 stream
    p += (size_t)ROWS * 256 * 2;                                   // (qkb slot, unused)
    p += (size_t)ROWS * 32 * 4 * 2 / 4;                            // (vtb slot, unused)
    __bf16* t0b  = (__bf16*)p;   p += (size_t)ROWS * E * 2;        // 8 MB attn out
    __bf16* wb   = (__bf16*)p;   p += (size_t)(N_IPW + 3 * N_SQ) * 2;
    float* part  = (float*)p;    p += (size_t)B * 8 * E * 4;

    __bf16* wb_ipw = wb;
    __bf16* wb_ow  = wb + N_IPW;
    __bf16* wb_w1  = wb_ow + N_SQ;
    __bf16* wb_w2  = wb_w1 + N_SQ;

    k_embedcvt<<<NCVT + ROWS / 16, 256, 0, stream>>>(
        ipw, ow, w1, w2, wb, x, emb_w, emb_b, hb);
    for (int L = 0; L < 3; ++L) {
        k_qkvattn<<<B * NH * 4, 512, 0, stream>>>(
            hb, wb_ipw + (size_t)L * 384 * 128, ipb + L * 384, t0b);
        k_layer2<<<ROWS / 64, 512, 0, stream>>>(
            t0b, wb_ow + (size_t)L * 128 * 128, ob + L * 128,
            ln1g + L * E, ln1b + L * E,
            wb_w1 + (size_t)L * 128 * 128, fb1 + L * 128,
            wb_w2 + (size_t)L * 128 * 128, fb2 + L * 128,
            ln2g + L * E, ln2b + L * E, hb);
    }
    k_pool1<<<B * 8, 256, 0, stream>>>(hb, mask, part);
    k_head<<<B, 256, 0, stream>>>(part, cw1, cb1, cw2, cb2, cw3, cb3, cw4, cb4,
                                  (float*)d_out);
}

// Round 10
// 296.545 us; speedup vs baseline: 2.9610x; 2.9610x over previous
//
#include <hip/hip_runtime.h>
#include <hip/hip_bf16.h>
#include <math.h>

#define B 32
#define S 1024
#define IN_DIM 16
#define E 128
#define NH 4
#define DH 32
#define HDIM 256
#define ROWS (B*S)   /* 32768 */
#define EPS 1e-5f

#define N_IPW (3*384*128)
#define N_SQ  (3*128*128)
#define NCVT ((N_IPW + 3*N_SQ) / 256)   /* 1152 cvt blocks */

typedef __bf16 bf16x8 __attribute__((ext_vector_type(8)));
typedef __bf16 bf16x4 __attribute__((ext_vector_type(4)));
typedef __bf16 bf16x2 __attribute__((ext_vector_type(2)));
typedef float f32x4 __attribute__((ext_vector_type(4)));
typedef float f32x16 __attribute__((ext_vector_type(16)));

#define MFMA16 __builtin_amdgcn_mfma_f32_16x16x32_bf16
#define MFMA32 __builtin_amdgcn_mfma_f32_32x32x16_bf16

union BF2U { bf16x2 b; unsigned int u; };
__device__ inline unsigned int pk2(float a, float b) {
    BF2U x; x.b[0] = (__bf16)a; x.b[1] = (__bf16)b; return x.u;
}

// 16B logical access as two 8B LDS ops.
union U8 { bf16x8 v8; bf16x4 v4[2]; unsigned u4[4]; };
__device__ inline void st8(__bf16* p, bf16x8 v) {
    U8 u; u.v8 = v;
    *(bf16x4*)p = u.v4[0];
    *(bf16x4*)(p + 4) = u.v4[1];
}
__device__ inline bf16x8 ld8(const __bf16* p) {
    U8 u;
    u.v4[0] = *(const bf16x4*)p;
    u.v4[1] = *(const bf16x4*)(p + 4);
    return u.v8;
}

// ---------------- fused weight-cvt + embed ----------------
__global__ __launch_bounds__(256) void k_embedcvt(
        const float* __restrict__ ipw, const float* __restrict__ ow,
        const float* __restrict__ w1, const float* __restrict__ w2,
        __bf16* __restrict__ wbo,
        const float* __restrict__ x, const float* __restrict__ W,
        const float* __restrict__ bias, __bf16* __restrict__ hb)
{
    int t = threadIdx.x;
    if (blockIdx.x < NCVT) {
        int i = blockIdx.x * 256 + t;
        float v;
        if (i < N_IPW) v = ipw[i];
        else if (i < N_IPW + N_SQ) v = ow[i - N_IPW];
        else if (i < N_IPW + 2 * N_SQ) v = w1[i - N_IPW - N_SQ];
        else v = w2[i - N_IPW - 2 * N_SQ];
        wbo[i] = (__bf16)v;
        return;
    }
    int row0 = (blockIdx.x - NCVT) * 16;
    __shared__ float xs[16][16];
    xs[t >> 4][t & 15] = x[(row0 + (t >> 4)) * IN_DIM + (t & 15)];
    __syncthreads();
    int sub = t >> 7, tc = t & 127;
    float w[16];
#pragma unroll
    for (int i = 0; i < 16; ++i) w[i] = W[tc * 16 + i];
    float bb = bias[tc];
#pragma unroll
    for (int rr = 0; rr < 8; ++rr) {
        int lr = sub * 8 + rr;
        float acc = bb;
#pragma unroll
        for (int i = 0; i < 16; ++i) acc += xs[lr][i] * w[i];
        hb[(size_t)(row0 + lr) * E + tc] = (__bf16)fmaxf(acc, 0.f);
    }
}

// ---------------- fused QKV-projection + flash attention (R10 = R5 revert) ----------------
// The proven 41.6 µs kernel: 8 waves x 64 q-rows (qt=2 ILP), grid 256,
// full-KV LDS (139 KB), VGPR 104 @ (512,2) — spill-free. Grid-512 LDS-split
// variants (R6-R9) all spilled f32x16 state (>128 VGPR demand) — abandoned
// per the R9 pre-commitment. VALU lsum (no ones-MFMA); Pm aliased into Ksh;
// c+1 register prefetch of aK/bVf.
__global__ __launch_bounds__(512, 2) void k_qkvattn(
        const __bf16* __restrict__ hb, const __bf16* __restrict__ Wip,
        const float* __restrict__ bip, __bf16* __restrict__ O)
{
    __shared__ __attribute__((aligned(16))) __bf16 Ksh[1024][36];
    __shared__ __attribute__((aligned(16))) __bf16 Vsh[32][1036];
    __shared__ float lscr[8][64];

    int t = threadIdx.x, lane = t & 63, wv = t >> 6;   // wv 0..7
    int l15 = lane & 15, quad = lane >> 4;
    int l31 = lane & 31, hi = lane >> 5;
    // XCD grouping: all 8 blocks sharing a b-panel land on the same XCD.
    int lb = ((blockIdx.x & 7) << 5) | (blockIdx.x >> 3);
    int half = lb & 1, bh = lb >> 1;
    int hh = bh & 3, b = bh >> 2;

    const __bf16* hpanel = hb + (size_t)b * S * E;

    // scale * log2(e) * 2^23 (Schraudolph pre-scale)
    const float qscale = 0.1767766952966369f * 1.4426950408889634f * 8388608.0f;
    const float C2 = 1065101558.0f;   // (127<<23) - 0.03*2^23
    f32x16 cinit16, z16;
#pragma unroll
    for (int i = 0; i < 16; ++i) { cinit16[i] = C2; z16[i] = 0.f; }

    // ---------- phase 1: Q for this wave's 64 rows (qt=2), 32x32 path ----------
    // D[q][d]: lane=d. One-time transpose to B-frag (lane=q, regs=d) via
    // per-(wave,qt) scratch slices aliased into Ksh rows [wv*128 + qt*32 ..).
    bf16x8 bQ[2][2];
    {
        bf16x8 bWq[8];
#pragma unroll
        for (int ch = 0; ch < 8; ++ch)
            bWq[ch] = *(const bf16x8*)&Wip[(size_t)(hh*32 + l31)*128 + ch*16 + hi*8];
        float bq = bip[hh*32 + l31];
#pragma unroll
        for (int qt = 0; qt < 2; ++qt) {
            int qrow0 = half*512 + wv*64 + qt*32;
            f32x16 aq = z16;
#pragma unroll
            for (int ch = 0; ch < 8; ++ch) {
                bf16x8 ah = *(const bf16x8*)&hpanel[(size_t)(qrow0 + l31)*128 + ch*16 + hi*8];
                aq = MFMA32(ah, bWq[ch], aq, 0, 0, 0);
            }
            __bf16* PmS = &Ksh[wv*128 + qt*32][0];   // [32][36] slice
#pragma unroll
            for (int r = 0; r < 16; ++r) {
                int q = (r & 3) + 8*(r >> 2) + 4*hi;
                PmS[q*36 + l31] = (__bf16)((aq[r] + bq) * qscale);
            }
        }
        __asm__ __volatile__("" ::: "memory");
#pragma unroll
        for (int qt = 0; qt < 2; ++qt) {
            const __bf16* PmS = &Ksh[wv*128 + qt*32][0];
            bQ[qt][0] = ld8(&PmS[l31*36 + hi*8]);
            bQ[qt][1] = ld8(&PmS[l31*36 + 16 + hi*8]);
        }
        __asm__ __volatile__("" ::: "memory");
    }
    __syncthreads();   // scratch rows are about to be overwritten by K fill

    // ---------- phase 2: K,V projection into LDS (barrier-free, 16x16) ----------
    {
        bf16x8 bWk[2][4], bWv[2][4];
#pragma unroll
        for (int df = 0; df < 2; ++df)
#pragma unroll
            for (int kc = 0; kc < 4; ++kc) {
                bWk[df][kc] = *(const bf16x8*)&Wip[(size_t)(128 + hh*32 + df*16 + l15)*128 + kc*32 + quad*8];
                bWv[df][kc] = *(const bf16x8*)&Wip[(size_t)(256 + hh*32 + df*16 + l15)*128 + kc*32 + quad*8];
            }
        float bk0 = bip[128 + hh*32 + l15],  bk1 = bip[128 + hh*32 + 16 + l15];
        float bvb0 = bip[256 + hh*32 + l15], bvb1 = bip[256 + hh*32 + 16 + l15];
        int srow = wv*16 + l15;   // 8 waves x 16 rows = 128 s-rows per iter
        bf16x8 af[4], ag[4];
#pragma unroll
        for (int kc = 0; kc < 4; ++kc)
            af[kc] = *(const bf16x8*)&hpanel[(size_t)srow*128 + kc*32 + quad*8];
        const f32x4 z4 = {0.f, 0.f, 0.f, 0.f};
        for (int c = 0; c < 8; ++c) {
            if (c < 7) {
#pragma unroll
                for (int kc = 0; kc < 4; ++kc)
                    ag[kc] = *(const bf16x8*)&hpanel[(size_t)((c+1)*128 + srow)*128 + kc*32 + quad*8];
            }
            f32x4 k0 = z4, k1 = z4, v0 = z4, v1 = z4;
#pragma unroll
            for (int kc = 0; kc < 4; ++kc) {
                k0 = MFMA16(af[kc], bWk[0][kc], k0, 0, 0, 0);
                k1 = MFMA16(af[kc], bWk[1][kc], k1, 0, 0, 0);
                v0 = MFMA16(af[kc], bWv[0][kc], v0, 0, 0, 0);
                v1 = MFMA16(af[kc], bWv[1][kc], v1, 0, 0, 0);
            }
            int s0 = c*128 + wv*16 + quad*4;
#pragma unroll
            for (int r = 0; r < 4; ++r) {
                Ksh[s0 + r][l15]      = (__bf16)(k0[r] + bk0);
                Ksh[s0 + r][16 + l15] = (__bf16)(k1[r] + bk1);
            }
            uint2 u0, u1;
            u0.x = pk2(v0[0] + bvb0, v0[1] + bvb0);
            u0.y = pk2(v0[2] + bvb0, v0[3] + bvb0);
            u1.x = pk2(v1[0] + bvb1, v1[1] + bvb1);
            u1.y = pk2(v1[2] + bvb1, v1[3] + bvb1);
            *(uint2*)&Vsh[l15][s0] = u0;
            *(uint2*)&Vsh[16 + l15][s0] = u1;
#pragma unroll
            for (int kc = 0; kc < 4; ++kc) af[kc] = ag[kc];
        }
    }
    __syncthreads();

    // ---------- phase 3: attention, fence-free, prefetched ----------
    f32x16 o[2];
    o[0] = z16; o[1] = z16;
    float lsum[2] = {0.f, 0.f};

    bf16x8 aK[2][2], bVf[4];
#pragma unroll
    for (int sub = 0; sub < 2; ++sub)
#pragma unroll
        for (int dh = 0; dh < 2; ++dh)
            aK[sub][dh] = ld8(&Ksh[sub*32 + l31][dh*16 + hi*8]);
#pragma unroll
    for (int ch = 0; ch < 4; ++ch) {
        U8 u;
        const __bf16* vp = &Vsh[l31][ch*16 + hi*4];
        u.v4[0] = *(const bf16x4*)vp;
        u.v4[1] = *(const bf16x4*)(vp + 8);
        bVf[ch] = u.v8;
    }

    for (int c = 0; c < 16; ++c) {
        bf16x8 aKn[2][2], bVn[4];
        if (c < 15) {
#pragma unroll
            for (int sub = 0; sub < 2; ++sub)
#pragma unroll
                for (int dh = 0; dh < 2; ++dh)
                    aKn[sub][dh] = ld8(&Ksh[(c+1)*64 + sub*32 + l31][dh*16 + hi*8]);
#pragma unroll
            for (int ch = 0; ch < 4; ++ch) {
                U8 u;
                const __bf16* vp = &Vsh[l31][(c+1)*64 + ch*16 + hi*4];
                u.v4[0] = *(const bf16x4*)vp;
                u.v4[1] = *(const bf16x4*)(vp + 8);
                bVn[ch] = u.v8;
            }
        }
#pragma unroll
        for (int qt = 0; qt < 2; ++qt) {
#pragma unroll
            for (int sub = 0; sub < 2; ++sub) {
                f32x16 acc = cinit16;
                acc = MFMA32(aK[sub][0], bQ[qt][0], acc, 0, 0, 0);
                acc = MFMA32(aK[sub][1], bQ[qt][1], acc, 0, 0, 0);
                // S[k][q] at lane(hi,q): k = 4hi + {0-3,8-11} (+16 for g=1).
                // Packed dwords are directly the PV A-frag; ints reinterpret
                // as f32 exp for the VALU row-sum.
#pragma unroll
                for (int g = 0; g < 2; ++g) {
                    U8 u;
                    float ls = 0.f;
#pragma unroll
                    for (int r = 0; r < 4; ++r) {
                        int ia = (int)acc[g*8 + 2*r];
                        int ib = (int)acc[g*8 + 2*r + 1];
                        u.u4[r] = __builtin_amdgcn_perm((unsigned)ib, (unsigned)ia, 0x07060302u);
                        ls += __int_as_float(ia) + __int_as_float(ib);
                    }
                    lsum[qt] += ls;
                    o[qt] = MFMA32(u.v8, bVf[sub*2 + g], o[qt], 0, 0, 0);
                }
            }
        }
        if (c < 15) {
#pragma unroll
            for (int sub = 0; sub < 2; ++sub)
#pragma unroll
                for (int dh = 0; dh < 2; ++dh)
                    aK[sub][dh] = aKn[sub][dh];
#pragma unroll
            for (int ch = 0; ch < 4; ++ch) bVf[ch] = bVn[ch];
        }
    }

    // ---------- epilogue: combine l halves, transpose 1/l via lscr ----------
#pragma unroll
    for (int qt = 0; qt < 2; ++qt) {
        float ls = lsum[qt] + __shfl_xor(lsum[qt], 32);
        if (hi == 0) lscr[wv][qt*32 + l31] = 1.f / ls;
    }
    __asm__ __volatile__("" ::: "memory");
#pragma unroll
    for (int qt = 0; qt < 2; ++qt)
#pragma unroll
        for (int r = 0; r < 16; ++r) {
            int q = (r & 3) + 8*(r >> 2) + 4*hi;
            float li = lscr[wv][qt*32 + q];
            int row = half*512 + wv*64 + qt*32 + q;
            O[((size_t)(b * S) + row) * E + hh*32 + l31] = (__bf16)(o[qt][r] * li);
        }
}

// ---------------- mega-fused: out-proj + res + LN1 + FFN1 + FFN2 + res + LN2 ----------------
// (512,2): grid is exactly 2 blocks/CU; cap 128, no spill.
__global__ __launch_bounds__(512, 2) void k_layer2(const __bf16* __restrict__ t0b,
        const __bf16* __restrict__ Wo, const float* __restrict__ ob,
        const float* __restrict__ g1, const float* __restrict__ bt1,
        const __bf16* __restrict__ W1, const float* __restrict__ b1v,
        const __bf16* __restrict__ W2, const float* __restrict__ b2v,
        const float* __restrict__ g2, const float* __restrict__ bt2,
        __bf16* __restrict__ hb)
{
    __shared__ __attribute__((aligned(16))) __bf16 As[64][132];
    __shared__ __attribute__((aligned(16))) __bf16 Ws[128][132];
    __shared__ float red[2][64][2];
    int t = threadIdx.x;
    int m0 = blockIdx.x * 64;
    int arow = t >> 3, acol = (t & 7) * 16;
    int wrow = t >> 2, wcol = (t & 3) * 32;
    {
        const __bf16* Ap = t0b + (size_t)(m0 + arow) * 128 + acol;
#pragma unroll
        for (int j = 0; j < 2; ++j)
            st8(&As[arow][acol + j * 8], *(const bf16x8*)&Ap[j * 8]);
        const __bf16* Wp = Wo + (size_t)wrow * 128 + wcol;
#pragma unroll
        for (int j = 0; j < 4; ++j)
            st8(&Ws[wrow][wcol + j * 8], *(const bf16x8*)&Wp[j * 8]);
    }
    __syncthreads();
    int lane = t & 63, wv = t >> 6;
    int l15 = lane & 15, quad = lane >> 4;
    int nh = wv & 1, mh = wv >> 1;   // mh 0..3: rows mh*16..+15
    f32x4 acc[4];

    // ---------- phase A: out-proj ----------
#pragma unroll
    for (int i = 0; i < 4; ++i) acc[i] = (f32x4){0.f, 0.f, 0.f, 0.f};
#pragma unroll
    for (int kc = 0; kc < 4; ++kc) {
        bf16x8 aw[4], ba;
#pragma unroll
        for (int nc = 0; nc < 4; ++nc)
            aw[nc] = ld8(&Ws[nh * 64 + nc * 16 + l15][kc * 32 + quad * 8]);
        ba = ld8(&As[mh * 16 + l15][kc * 32 + quad * 8]);
#pragma unroll
        for (int nc = 0; nc < 4; ++nc)
            acc[nc] = MFMA16(aw[nc], ba, acc[nc], 0, 0, 0);
    }
    float s1 = 0.f, s2 = 0.f;
    int m = m0 + mh * 16 + l15;
#pragma unroll
    for (int nc = 0; nc < 4; ++nc) {
        float4 bv = *(const float4*)&ob[nh * 64 + nc * 16 + quad * 4];
        bf16x4 rv = *(const bf16x4*)&hb[(size_t)m * 128 + nh * 64 + nc * 16 + quad * 4];
        acc[nc][0] += bv.x + (float)rv[0];
        acc[nc][1] += bv.y + (float)rv[1];
        acc[nc][2] += bv.z + (float)rv[2];
        acc[nc][3] += bv.w + (float)rv[3];
#pragma unroll
        for (int i = 0; i < 4; ++i) {
            s1 += acc[nc][i];
            s2 += acc[nc][i] * acc[nc][i];
        }
    }
    s1 += __shfl_xor(s1, 16); s1 += __shfl_xor(s1, 32);
    s2 += __shfl_xor(s2, 16); s2 += __shfl_xor(s2, 32);
    if (quad == 0) {
        red[nh][mh * 16 + l15][0] = s1;
        red[nh][mh * 16 + l15][1] = s2;
    }
    __syncthreads();
    float mu, rs;
    {
        int r = mh * 16 + l15;
        float S1 = red[0][r][0] + red[1][r][0];
        float S2 = red[0][r][1] + red[1][r][1];
        mu = S1 * (1.f / 128.f);
        float var = S2 * (1.f / 128.f) - mu * mu;
        rs = rsqrtf(var + EPS);
    }
    bf16x4 res2[4];
#pragma unroll
    for (int nc = 0; nc < 4; ++nc) {
        float4 gv = *(const float4*)&g1[nh * 64 + nc * 16 + quad * 4];
        float4 bb = *(const float4*)&bt1[nh * 64 + nc * 16 + quad * 4];
        float o0 = (acc[nc][0] - mu) * rs * gv.x + bb.x;
        float o1 = (acc[nc][1] - mu) * rs * gv.y + bb.y;
        float o2 = (acc[nc][2] - mu) * rs * gv.z + bb.z;
        float o3 = (acc[nc][3] - mu) * rs * gv.w + bb.w;
        bf16x4 xb;
        xb[0] = (__bf16)o0; xb[1] = (__bf16)o1;
        xb[2] = (__bf16)o2; xb[3] = (__bf16)o3;
        res2[nc] = xb;
        *(bf16x4*)&As[mh * 16 + l15][nh * 64 + nc * 16 + quad * 4] = xb;
    }
    {
        const __bf16* Wp = W1 + (size_t)wrow * 128 + wcol;
#pragma unroll
        for (int j = 0; j < 4; ++j)
            st8(&Ws[wrow][wcol + j * 8], *(const bf16x8*)&Wp[j * 8]);
    }
    __syncthreads();

    // ---------- phase B: FFN1 ----------
#pragma unroll
    for (int i = 0; i < 4; ++i) acc[i] = (f32x4){0.f, 0.f, 0.f, 0.f};
#pragma unroll
    for (int kc = 0; kc < 4; ++kc) {
        bf16x8 aw[4], ba;
#pragma unroll
        for (int nc = 0; nc < 4; ++nc)
            aw[nc] = ld8(&Ws[nh * 64 + nc * 16 + l15][kc * 32 + quad * 8]);
        ba = ld8(&As[mh * 16 + l15][kc * 32 + quad * 8]);
#pragma unroll
        for (int nc = 0; nc < 4; ++nc)
            acc[nc] = MFMA16(aw[nc], ba, acc[nc], 0, 0, 0);
    }
    __syncthreads();
#pragma unroll
    for (int nc = 0; nc < 4; ++nc) {
        float4 bv = *(const float4*)&b1v[nh * 64 + nc * 16 + quad * 4];
        float v0 = fmaxf(acc[nc][0] + bv.x, 0.f);
        float v1 = fmaxf(acc[nc][1] + bv.y, 0.f);
        float v2 = fmaxf(acc[nc][2] + bv.z, 0.f);
        float v3 = fmaxf(acc[nc][3] + bv.w, 0.f);
        uint2 u; u.x = pk2(v0, v1); u.y = pk2(v2, v3);
        *(uint2*)&As[mh * 16 + l15][nh * 64 + nc * 16 + quad * 4] = u;
    }
    {
        const __bf16* Wp = W2 + (size_t)wrow * 128 + wcol;
#pragma unroll
        for (int j = 0; j < 4; ++j)
            st8(&Ws[wrow][wcol + j * 8], *(const bf16x8*)&Wp[j * 8]);
    }
    __syncthreads();

    // ---------- phase C: FFN2 + res2 + LN2 ----------
#pragma unroll
    for (int i = 0; i < 4; ++i) acc[i] = (f32x4){0.f, 0.f, 0.f, 0.f};
#pragma unroll
    for (int kc = 0; kc < 4; ++kc) {
        bf16x8 aw[4], ba;
#pragma unroll
        for (int nc = 0; nc < 4; ++nc)
            aw[nc] = ld8(&Ws[nh * 64 + nc * 16 + l15][kc * 32 + quad * 8]);
        ba = ld8(&As[mh * 16 + l15][kc * 32 + quad * 8]);
#pragma unroll
        for (int nc = 0; nc < 4; ++nc)
            acc[nc] = MFMA16(aw[nc], ba, acc[nc], 0, 0, 0);
    }
    s1 = 0.f; s2 = 0.f;
#pragma unroll
    for (int nc = 0; nc < 4; ++nc) {
        float4 bv = *(const float4*)&b2v[nh * 64 + nc * 16 + quad * 4];
        acc[nc][0] += bv.x + (float)res2[nc][0];
        acc[nc][1] += bv.y + (float)res2[nc][1];
        acc[nc][2] += bv.z + (float)res2[nc][2];
        acc[nc][3] += bv.w + (float)res2[nc][3];
#pragma unroll
        for (int i = 0; i < 4; ++i) {
            s1 += acc[nc][i];
            s2 += acc[nc][i] * acc[nc][i];
        }
    }
    s1 += __shfl_xor(s1, 16); s1 += __shfl_xor(s1, 32);
    s2 += __shfl_xor(s2, 16); s2 += __shfl_xor(s2, 32);
    if (quad == 0) {
        red[nh][mh * 16 + l15][0] = s1;
        red[nh][mh * 16 + l15][1] = s2;
    }
    __syncthreads();
    {
        int r = mh * 16 + l15;
        float S1 = red[0][r][0] + red[1][r][0];
        float S2 = red[0][r][1] + red[1][r][1];
        mu = S1 * (1.f / 128.f);
        float var = S2 * (1.f / 128.f) - mu * mu;
        rs = rsqrtf(var + EPS);
    }
#pragma unroll
    for (int nc = 0; nc < 4; ++nc) {
        float4 gv = *(const float4*)&g2[nh * 64 + nc * 16 + quad * 4];
        float4 bb = *(const float4*)&bt2[nh * 64 + nc * 16 + quad * 4];
        float o0 = (acc[nc][0] - mu) * rs * gv.x + bb.x;
        float o1 = (acc[nc][1] - mu) * rs * gv.y + bb.y;
        float o2 = (acc[nc][2] - mu) * rs * gv.z + bb.z;
        float o3 = (acc[nc][3] - mu) * rs * gv.w + bb.w;
        uint2 u; u.x = pk2(o0, o1); u.y = pk2(o2, o3);
        *(uint2*)&hb[(size_t)m * 128 + nh * 64 + nc * 16 + quad * 4] = u;
    }
}

// ---------------- masked sum pool stage 1 (bf16 h, vectorized) ----------------
__global__ __launch_bounds__(256) void k_pool1(const __bf16* __restrict__ h,
        const float* __restrict__ mask, float* __restrict__ part)
{
    int bx = blockIdx.x;
    int b = bx >> 3, ch = bx & 7, t = threadIdx.x;
    int sg = t >> 4, cg = t & 15;
    __shared__ float red[16][128];
    float acc[8];
#pragma unroll
    for (int j = 0; j < 8; ++j) acc[j] = 0.f;
    const __bf16* hp = h + ((size_t)(b * S + ch * 128 + sg)) * E + cg * 8;
    const float* mp = mask + b * S + ch * 128 + sg;
#pragma unroll
    for (int k = 0; k < 8; ++k) {
        float m = mp[k * 16];
        bf16x8 hv = *(const bf16x8*)&hp[(size_t)(k * 16) * E];
#pragma unroll
        for (int j = 0; j < 8; ++j) acc[j] += (float)hv[j] * m;
    }
#pragma unroll
    for (int j = 0; j < 8; ++j) red[sg][cg * 8 + j] = acc[j];
    __syncthreads();
    if (t < 128) {
        float a = 0.f;
#pragma unroll
        for (int sgi = 0; sgi < 16; ++sgi) a += red[sgi][t];
        part[(size_t)bx * E + t] = a;
    }
}

// ---------------- fused head: pool2 + cls1..3 + final sigmoid ----------------
__global__ __launch_bounds__(256) void k_head(const float* __restrict__ part,
        const float* __restrict__ cw1, const float* __restrict__ cb1,
        const float* __restrict__ cw2, const float* __restrict__ cb2,
        const float* __restrict__ cw3, const float* __restrict__ cb3,
        const float* __restrict__ cw4, const float* __restrict__ cb4,
        float* __restrict__ out)
{
    int b = blockIdx.x, t = threadIdx.x;
    __shared__ float p[128], za[256], zb[256];
    __shared__ float red4[4];
    if (t < 128) {
        float a = 0.f;
#pragma unroll
        for (int c = 0; c < 8; ++c) a += part[(size_t)(b * 8 + c) * 128 + t];
        p[t] = a;
    }
    __syncthreads();
    float a1 = cb1[t];
    for (int k = 0; k < 128; ++k) a1 += p[k] * cw1[t * 128 + k];
    za[t] = fmaxf(a1, 0.f);
    __syncthreads();
    float a2 = cb2[t];
    for (int k = 0; k < 256; ++k) a2 += za[k] * cw2[t * 256 + k];
    zb[t] = fmaxf(a2, 0.f);
    __syncthreads();
    float a3 = cb3[t];
    for (int k = 0; k < 256; ++k) a3 += zb[k] * cw3[t * 256 + k];
    float z3 = fmaxf(a3, 0.f);
    float prt = z3 * cw4[t];
#pragma unroll
    for (int o2 = 32; o2; o2 >>= 1) prt += __shfl_xor(prt, o2);
    if ((t & 63) == 0) red4[t >> 6] = prt;
    __syncthreads();
    if (t == 0) {
        float sum = red4[0] + red4[1] + red4[2] + red4[3] + cb4[0];
        out[b] = 1.f / (1.f + __expf(-sum));
    }
}

extern "C" void kernel_launch(void* const* d_in, const int* in_sizes, int n_in,
                              void* d_out, int out_size, void* d_ws, size_t ws_size,
                              hipStream_t stream)
{
    const float* x     = (const float*)d_in[0];
    const float* mask  = (const float*)d_in[1];
    const float* emb_w = (const float*)d_in[2];
    const float* emb_b = (const float*)d_in[3];
    const float* ipw   = (const float*)d_in[4];
    const float* ipb   = (const float*)d_in[5];
    const float* ow    = (const float*)d_in[6];
    const float* ob    = (const float*)d_in[7];
    const float* ln1g  = (const float*)d_in[8];
    const float* ln1b  = (const float*)d_in[9];
    const float* ln2g  = (const float*)d_in[10];
    const float* ln2b  = (const float*)d_in[11];
    const float* w1    = (const float*)d_in[12];
    const float* fb1   = (const float*)d_in[13];
    const float* w2    = (const float*)d_in[14];
    const float* fb2   = (const float*)d_in[15];
    const float* cw1   = (const float*)d_in[16];
    const float* cb1   = (const float*)d_in[17];
    const float* cw2   = (const float*)d_in[18];
    const float* cb2   = (const float*)d_in[19];
    const float* cw3   = (const float*)d_in[20];
    const float* cb3   = (const float*)d_in[21];
    const float* cw4   = (const float*)d_in[22];
    const float* cb4   = (const float*)d_in[23];

    char* p = (char*)d_ws;
    __bf16* hb   = (__bf16*)p;   p += (size_t)ROWS * E * 2;        // 8 MB bf16 stream
    p += (size_t)ROWS * 256 * 2;                                   // (qkb slot, unused)
    p += (size_t)ROWS * 32 * 4 * 2 / 4;                            // (vtb slot, unused)
    __bf16* t0b  = (__bf16*)p;   p += (size_t)ROWS * E * 2;        // 8 MB attn out
    __bf16* wb   = (__bf16*)p;   p += (size_t)(N_IPW + 3 * N_SQ) * 2;
    float* part  = (float*)p;    p += (size_t)B * 8 * E * 4;

    __bf16* wb_ipw = wb;
    __bf16* wb_ow  = wb + N_IPW;
    __bf16* wb_w1  = wb_ow + N_SQ;
    __bf16* wb_w2  = wb_w1 + N_SQ;

    k_embedcvt<<<NCVT + ROWS / 16, 256, 0, stream>>>(
        ipw, ow, w1, w2, wb, x, emb_w, emb_b, hb);
    for (int L = 0; L < 3; ++L) {
        k_qkvattn<<<B * NH * 2, 512, 0, stream>>>(
            hb, wb_ipw + (size_t)L * 384 * 128, ipb + L * 384, t0b);
        k_layer2<<<ROWS / 64, 512, 0, stream>>>(
            t0b, wb_ow + (size_t)L * 128 * 128, ob + L * 128,
            ln1g + L * E, ln1b + L * E,
            wb_w1 + (size_t)L * 128 * 128, fb1 + L * 128,
            wb_w2 + (size_t)L * 128 * 128, fb2 + L * 128,
            ln2g + L * E, ln2b + L * E, hb);
    }
    k_pool1<<<B * 8, 256, 0, stream>>>(hb, mask, part);
    k_head<<<B, 256, 0, stream>>>(part, cw1, cb1, cw2, cb2, cw3, cb3, cw4, cb4,
                                  (float*)d_out);
}